// Round 4
// baseline (256.669 us; speedup 1.0000x reference)
//
#include <hip/hip_runtime.h>
#include <stdint.h>

#define M_DIM 8192   // K of the Gram GEMM
#define N_DIM 4096   // output N x N
#define NT32 (M_DIM / 32)  // 256 K-tiles of 32

typedef __attribute__((ext_vector_type(4))) float f32x4;
typedef __attribute__((ext_vector_type(8))) short bf16x8;

__device__ __forceinline__ ushort f2bf(float x) {
  union { float f; uint32_t u; } v;
  v.f = x;
  uint32_t r = (v.u + 0x7fffu + ((v.u >> 16) & 1u)) >> 16;
  return (ushort)r;
}

__device__ __forceinline__ void gl_lds16b(const char* g, char* l) {
  __builtin_amdgcn_global_load_lds(
      (const __attribute__((address_space(1))) void*)g,
      (__attribute__((address_space(3))) void*)l, 16, 0, 0);
}

#define CFENCE asm volatile("" ::: "memory")

// ---------------- Kernel 1: A[M][N] fp32 -> At[N][M] bf16
__global__ __launch_bounds__(256) void transpose_convert(
    const float* __restrict__ A, ushort* __restrict__ At) {
  __shared__ ushort tile[64][66];
  const int bm = blockIdx.x % (M_DIM / 64);
  const int bn = blockIdx.x / (M_DIM / 64);
  const int m0 = bm * 64, n0 = bn * 64;
  const int t = threadIdx.x;
  const int tr = t >> 4;
  const int tc = (t & 15) << 2;
#pragma unroll
  for (int p = 0; p < 4; ++p) {
    const int r = p * 16 + tr;
    const float4 v = *reinterpret_cast<const float4*>(
        &A[(size_t)(m0 + r) * N_DIM + (n0 + tc)]);
    tile[tc + 0][r] = f2bf(v.x);
    tile[tc + 1][r] = f2bf(v.y);
    tile[tc + 2][r] = f2bf(v.z);
    tile[tc + 3][r] = f2bf(v.w);
  }
  __syncthreads();
#pragma unroll
  for (int p = 0; p < 4; ++p) {
    const int rn = p * 16 + tr;
    ushort4 o;
    o.x = tile[rn][tc + 0];
    o.y = tile[rn][tc + 1];
    o.z = tile[rn][tc + 2];
    o.w = tile[rn][tc + 3];
    *reinterpret_cast<ushort4*>(
        &At[(size_t)(n0 + rn) * M_DIM + (m0 + tc)]) = o;
  }
}

// ---------------- Kernel 2: 256x256 tile, BK=32, 4 LDS bufs,
// ONE barrier + counted vmcnt(8) per K-tile, compiler-scheduled read/MFMA overlap.
// LDS buf b (base b*32768): A 256x32 bf16 @0 (16KB), B @16384.
// Swizzle: byte d -> d ^ ((d>>6)&3)<<4  (involution, 64B row stride).
__global__ __launch_bounds__(512, 1) void gram1b(
    const ushort* __restrict__ At, float* __restrict__ C) {
  __shared__ char smem[131072];

  const int bid = (int)blockIdx.x;
  const int wg = (bid & 7) * 32 + (bid >> 3);  // XCD swizzle (256 % 8 == 0)
  const int bi = wg >> 4, bj = wg & 15;

  const int t = (int)threadIdx.x;
  const int lane = t & 63, wave = t >> 6;
  const int wr = wave >> 2, wc = wave & 3;   // wave tile: rows wr*128, cols wc*64
  const int fr = lane & 15, fq = lane >> 4;

  // ---- fragment read offsets within a buffer (swizzled)
  const int colr = (fq * 16) ^ ((fr & 3) << 4);  // row&3 == fr&3 for all frags
  int adA[8], adB[4];
#pragma unroll
  for (int m = 0; m < 8; ++m)
    adA[m] = (wr * 128 + m * 16 + fr) * 64 + colr;
#pragma unroll
  for (int n = 0; n < 4; ++n)
    adB[n] = 16384 + (wc * 64 + n * 16 + fr) * 64 + colr;

  // ---- staging: linear LDS dest d = t*16 (+8192 for rows 128-255),
  //      pre-swizzled global source column
  const char* const Atb = (const char*)At;
  const size_t MB = (size_t)M_DIM * 2;  // bytes per At row
  const int rq = t >> 2;                               // 0..127
  const int cs = ((t & 3) * 16) ^ ((rq & 3) << 4);     // swizzled col byte
  const char* const sA0 = Atb + (size_t)(bi * 256 + rq) * MB + cs;
  const char* const sA1 = Atb + (size_t)(bi * 256 + 128 + rq) * MB + cs;
  const char* const sB0 = Atb + (size_t)(bj * 256 + rq) * MB + cs;
  const char* const sB1 = Atb + (size_t)(bj * 256 + 128 + rq) * MB + cs;
  const int d0 = t * 16, d1 = 8192 + t * 16;

  f32x4 acc[8][4] = {};

  // ---- prologue: stage tiles 0,1,2 into bufs 0,1,2 (12 gl_lds)
#pragma unroll
  for (int ss = 0; ss < 3; ++ss) {
    char* const b = smem + ss * 32768;
    const size_t ko = (size_t)ss * 64;
    gl_lds16b(sA0 + ko, b + d0);
    gl_lds16b(sA1 + ko, b + d1);
    gl_lds16b(sB0 + ko, b + 16384 + d0);
    gl_lds16b(sB1 + ko, b + 16384 + d1);
  }

#define ITER(S, STG, VMW) do {                                               \
  if ((VMW) == 8)      asm volatile("s_waitcnt vmcnt(8)" ::: "memory");      \
  else if ((VMW) == 4) asm volatile("s_waitcnt vmcnt(4)" ::: "memory");      \
  else if ((VMW) == 0) asm volatile("s_waitcnt vmcnt(0)" ::: "memory");      \
  __builtin_amdgcn_s_barrier();                                              \
  CFENCE;                                                                    \
  {                                                                          \
    const char* const bb = smem + ((S) & 3) * 32768;                         \
    bf16x8 a[8], b[4];                                                       \
    _Pragma("unroll") for (int m = 0; m < 8; ++m)                            \
      a[m] = *reinterpret_cast<const bf16x8*>(bb + adA[m]);                  \
    _Pragma("unroll") for (int n = 0; n < 4; ++n)                            \
      b[n] = *reinterpret_cast<const bf16x8*>(bb + adB[n]);                  \
    if (STG) {                                                               \
      char* const sbf = smem + (((S) + 3) & 3) * 32768;                      \
      const size_t ko = (size_t)((S) + 3) * 64;                              \
      gl_lds16b(sA0 + ko, sbf + d0);                                         \
      gl_lds16b(sA1 + ko, sbf + d1);                                         \
      gl_lds16b(sB0 + ko, sbf + 16384 + d0);                                 \
      gl_lds16b(sB1 + ko, sbf + 16384 + d1);                                 \
    }                                                                        \
    _Pragma("unroll") for (int m = 0; m < 8; ++m)                            \
      _Pragma("unroll") for (int n = 0; n < 4; ++n)                          \
        acc[m][n] = __builtin_amdgcn_mfma_f32_16x16x32_bf16(                 \
            a[m], b[n], acc[m][n], 0, 0, 0);                                 \
  }                                                                          \
} while (0)

  // main loop: 252 staged iters (unrolled x4 -> compile-time buf offsets)
  for (int s = 0; s < 252; s += 4) {
    ITER(s + 0, true, 8);
    ITER(s + 1, true, 8);
    ITER(s + 2, true, 8);
    ITER(s + 3, true, 8);
  }
  ITER(252, true, 8);    // stages tile 255
  ITER(253, false, 8);
  ITER(254, false, 4);
  ITER(255, false, 0);

#undef ITER

  // ---- epilogue: C/D map col=lane&15, row=fq*4+j (verified R1-R3)
  const int rb = bi * 256 + wr * 128;
  const int cb = bj * 256 + wc * 64;
#pragma unroll
  for (int m = 0; m < 8; ++m) {
    const int r0 = rb + m * 16 + fq * 4;
#pragma unroll
    for (int n = 0; n < 4; ++n) {
      const int c = cb + n * 16 + fr;
#pragma unroll
      for (int j = 0; j < 4; ++j)
        C[(size_t)(r0 + j) * N_DIM + c] = acc[m][n][j];
    }
  }
}

extern "C" void kernel_launch(void* const* d_in, const int* in_sizes, int n_in,
                              void* d_out, int out_size, void* d_ws, size_t ws_size,
                              hipStream_t stream) {
  const float* A = (const float*)d_in[0];
  float* C = (float*)d_out;
  ushort* At = (ushort*)d_ws;  // 64 MiB

  transpose_convert<<<dim3((M_DIM / 64) * (N_DIM / 64)), 256, 0, stream>>>(A, At);
  gram1b<<<dim3(16 * 16), 512, 0, stream>>>(At, C);
}

// Round 5
// 247.893 us; speedup vs baseline: 1.0354x; 1.0354x over previous
//
#include <hip/hip_runtime.h>
#include <stdint.h>

#define M_DIM 8192   // K of the Gram GEMM
#define N_DIM 4096   // output N x N

typedef __attribute__((ext_vector_type(4))) float f32x4;
typedef __attribute__((ext_vector_type(8))) short bf16x8;

__device__ __forceinline__ ushort f2bf(float x) {
  union { float f; uint32_t u; } v;
  v.f = x;
  uint32_t r = (v.u + 0x7fffu + ((v.u >> 16) & 1u)) >> 16;
  return (ushort)r;
}

__device__ __forceinline__ void gl_lds16b(const char* g, char* l) {
  __builtin_amdgcn_global_load_lds(
      (const __attribute__((address_space(1))) void*)g,
      (__attribute__((address_space(3))) void*)l, 16, 0, 0);
}

#define CFENCE asm volatile("" ::: "memory")

// ---------------- Kernel 1: A[M][N] fp32 -> At[N][M] bf16
__global__ __launch_bounds__(256) void transpose_convert(
    const float* __restrict__ A, ushort* __restrict__ At) {
  __shared__ ushort tile[64][66];
  const int bm = blockIdx.x % (M_DIM / 64);
  const int bn = blockIdx.x / (M_DIM / 64);
  const int m0 = bm * 64, n0 = bn * 64;
  const int t = threadIdx.x;
  const int tr = t >> 4;
  const int tc = (t & 15) << 2;
#pragma unroll
  for (int p = 0; p < 4; ++p) {
    const int r = p * 16 + tr;
    const float4 v = *reinterpret_cast<const float4*>(
        &A[(size_t)(m0 + r) * N_DIM + (n0 + tc)]);
    tile[tc + 0][r] = f2bf(v.x);
    tile[tc + 1][r] = f2bf(v.y);
    tile[tc + 2][r] = f2bf(v.z);
    tile[tc + 3][r] = f2bf(v.w);
  }
  __syncthreads();
#pragma unroll
  for (int p = 0; p < 4; ++p) {
    const int rn = p * 16 + tr;
    ushort4 o;
    o.x = tile[rn][tc + 0];
    o.y = tile[rn][tc + 1];
    o.z = tile[rn][tc + 2];
    o.w = tile[rn][tc + 3];
    *reinterpret_cast<ushort4*>(
        &At[(size_t)(n0 + rn) * M_DIM + (m0 + tc)]) = o;
  }
}

// ---------------- Kernel 2: 256x256 tile, BK=32, 4 LDS bufs,
// ONE barrier + counted vmcnt(8) per K-tile (R4 schedule, unchanged).
// NEW swizzle: byte d -> d ^ ((d>>7)&3)<<4  (XOR col-slot with row bits 1-2).
// Bank proof: 8-lane subgroup bank_start = (fr&1)*16 + 4*(fq^((fr>>1)&3))
//   -> 8 disjoint 4-bank spans covering all 32 banks. Involution: bits 7-8
//   untouched by the XOR.
__global__ __launch_bounds__(512, 1) void gram1b(
    const ushort* __restrict__ At, float* __restrict__ C) {
  __shared__ char smem[131072];

  const int bid = (int)blockIdx.x;
  const int wg = (bid & 7) * 32 + (bid >> 3);  // XCD swizzle (256 % 8 == 0)
  const int bi = wg >> 4, bj = wg & 15;

  const int t = (int)threadIdx.x;
  const int lane = t & 63, wave = t >> 6;
  const int wr = wave >> 2, wc = wave & 3;   // wave tile: rows wr*128, cols wc*64
  const int fr = lane & 15, fq = lane >> 4;

  // ---- fragment read offsets within a buffer (swizzled)
  // row % 4 == fr % 4 for every fragment row (m*16, n*16, wr*128, wc*64 all
  // multiples of 4 rows), so (row>>1)&3 == (fr>>1)&3: loop-invariant col.
  const int colr = (fq * 16) ^ (((fr >> 1) & 3) << 4);
  int adA[8], adB[4];
#pragma unroll
  for (int m = 0; m < 8; ++m)
    adA[m] = (wr * 128 + m * 16 + fr) * 64 + colr;
#pragma unroll
  for (int n = 0; n < 4; ++n)
    adB[n] = 16384 + (wc * 64 + n * 16 + fr) * 64 + colr;

  // ---- staging: linear LDS dest d = t*16 (+8192 for rows 128-255).
  // LDS[d] must hold data[swz(d)]; swz(d)=d^((d>>7)&3)<<4, d=t*16 ->
  // source col = 16*((t&3) ^ ((t>>3)&3)). Same for the +8192 half
  // (8192>>7 = 64, &3 = 0).
  const char* const Atb = (const char*)At;
  const size_t MB = (size_t)M_DIM * 2;  // bytes per At row
  const int rq = t >> 2;                               // 0..127
  const int cs = ((t & 3) ^ ((t >> 3) & 3)) * 16;      // swizzled col byte
  const char* const sA0 = Atb + (size_t)(bi * 256 + rq) * MB + cs;
  const char* const sA1 = Atb + (size_t)(bi * 256 + 128 + rq) * MB + cs;
  const char* const sB0 = Atb + (size_t)(bj * 256 + rq) * MB + cs;
  const char* const sB1 = Atb + (size_t)(bj * 256 + 128 + rq) * MB + cs;
  const int d0 = t * 16, d1 = 8192 + t * 16;

  f32x4 acc[8][4] = {};

  // ---- prologue: stage tiles 0,1,2 into bufs 0,1,2 (12 gl_lds)
#pragma unroll
  for (int ss = 0; ss < 3; ++ss) {
    char* const b = smem + ss * 32768;
    const size_t ko = (size_t)ss * 64;
    gl_lds16b(sA0 + ko, b + d0);
    gl_lds16b(sA1 + ko, b + d1);
    gl_lds16b(sB0 + ko, b + 16384 + d0);
    gl_lds16b(sB1 + ko, b + 16384 + d1);
  }

#define ITER(S, STG, VMW) do {                                               \
  if ((VMW) == 8)      asm volatile("s_waitcnt vmcnt(8)" ::: "memory");      \
  else if ((VMW) == 4) asm volatile("s_waitcnt vmcnt(4)" ::: "memory");      \
  else if ((VMW) == 0) asm volatile("s_waitcnt vmcnt(0)" ::: "memory");      \
  __builtin_amdgcn_s_barrier();                                              \
  CFENCE;                                                                    \
  {                                                                          \
    const char* const bb = smem + ((S) & 3) * 32768;                         \
    bf16x8 a[8], b[4];                                                       \
    _Pragma("unroll") for (int m = 0; m < 8; ++m)                            \
      a[m] = *reinterpret_cast<const bf16x8*>(bb + adA[m]);                  \
    _Pragma("unroll") for (int n = 0; n < 4; ++n)                            \
      b[n] = *reinterpret_cast<const bf16x8*>(bb + adB[n]);                  \
    if (STG) {                                                               \
      char* const sbf = smem + (((S) + 3) & 3) * 32768;                      \
      const size_t ko = (size_t)((S) + 3) * 64;                              \
      gl_lds16b(sA0 + ko, sbf + d0);                                         \
      gl_lds16b(sA1 + ko, sbf + d1);                                         \
      gl_lds16b(sB0 + ko, sbf + 16384 + d0);                                 \
      gl_lds16b(sB1 + ko, sbf + 16384 + d1);                                 \
    }                                                                        \
    _Pragma("unroll") for (int m = 0; m < 8; ++m)                            \
      _Pragma("unroll") for (int n = 0; n < 4; ++n)                          \
        acc[m][n] = __builtin_amdgcn_mfma_f32_16x16x32_bf16(                 \
            a[m], b[n], acc[m][n], 0, 0, 0);                                 \
  }                                                                          \
} while (0)

  // main loop: 252 staged iters (unrolled x4 -> compile-time buf offsets)
  for (int s = 0; s < 252; s += 4) {
    ITER(s + 0, true, 8);
    ITER(s + 1, true, 8);
    ITER(s + 2, true, 8);
    ITER(s + 3, true, 8);
  }
  ITER(252, true, 8);    // stages tile 255
  ITER(253, false, 8);
  ITER(254, false, 4);
  ITER(255, false, 0);

#undef ITER

  // ---- epilogue: C/D map col=lane&15, row=fq*4+j (verified R1-R4)
  const int rb = bi * 256 + wr * 128;
  const int cb = bj * 256 + wc * 64;
#pragma unroll
  for (int m = 0; m < 8; ++m) {
    const int r0 = rb + m * 16 + fq * 4;
#pragma unroll
    for (int n = 0; n < 4; ++n) {
      const int c = cb + n * 16 + fr;
#pragma unroll
      for (int j = 0; j < 4; ++j)
        C[(size_t)(r0 + j) * N_DIM + c] = acc[m][n][j];
    }
  }
}

extern "C" void kernel_launch(void* const* d_in, const int* in_sizes, int n_in,
                              void* d_out, int out_size, void* d_ws, size_t ws_size,
                              hipStream_t stream) {
  const float* A = (const float*)d_in[0];
  float* C = (float*)d_out;
  ushort* At = (ushort*)d_ws;  // 64 MiB

  transpose_convert<<<dim3((M_DIM / 64) * (N_DIM / 64)), 256, 0, stream>>>(A, At);
  gram1b<<<dim3(16 * 16), 512, 0, stream>>>(At, C);
}